// Round 2
// baseline (2435.017 us; speedup 1.0000x reference)
//
#include <hip/hip_runtime.h>

// ---------- helpers ----------
__device__ __forceinline__ unsigned enc_f32(float f) {
    unsigned u = __float_as_uint(f);
    return (u & 0x80000000u) ? ~u : (u | 0x80000000u);
}
__device__ __forceinline__ float dec_f32(unsigned e) {
    return (e & 0x80000000u) ? __uint_as_float(e & 0x7fffffffu) : __uint_as_float(~e);
}

// ---------- zero fill (grid-stride) ----------
__global__ __launch_bounds__(256) void zero_fill(float* __restrict__ p, size_t n) {
    size_t i = blockIdx.x * 256llu + threadIdx.x;
    size_t stride = (size_t)gridDim.x * 256llu;
    for (; i < n; i += stride) p[i] = 0.f;
}

// ---------- GEMM: C[M,64] (+)= A[M,K] @ B[K,64] ----------
template<bool ACC>
__global__ __launch_bounds__(256) void gemm64(const float* __restrict__ A,
                                              const float* __restrict__ B,
                                              float* __restrict__ C,
                                              int M, int K, int lda, int ldb, int ldc) {
    const int BM = 64, BN = 64, BK = 32;
    __shared__ float As[BM][BK + 1];
    __shared__ float Bs[BK][BN + 1];
    const int tid = threadIdx.x;
    const int tx = tid & 15, ty = tid >> 4;
    const int row0 = blockIdx.x * BM;
    float acc[4][4] = {};
    for (int k0 = 0; k0 < K; k0 += BK) {
        for (int i = tid; i < BM * BK; i += 256) {
            int r = i >> 5, c = i & 31;
            int gr = row0 + r;
            As[r][c] = (gr < M) ? A[(size_t)gr * lda + k0 + c] : 0.f;
        }
        for (int i = tid; i < BK * BN; i += 256) {
            int r = i >> 6, c = i & 63;
            Bs[r][c] = B[(size_t)(k0 + r) * ldb + c];
        }
        __syncthreads();
#pragma unroll
        for (int k = 0; k < BK; ++k) {
            float a[4], b[4];
#pragma unroll
            for (int i = 0; i < 4; ++i) a[i] = As[ty * 4 + i][k];
#pragma unroll
            for (int j = 0; j < 4; ++j) b[j] = Bs[k][tx * 4 + j];
#pragma unroll
            for (int i = 0; i < 4; ++i)
#pragma unroll
                for (int j = 0; j < 4; ++j) acc[i][j] += a[i] * b[j];
        }
        __syncthreads();
    }
#pragma unroll
    for (int i = 0; i < 4; ++i) {
        int gr = row0 + ty * 4 + i;
        if (gr >= M) continue;
#pragma unroll
        for (int j = 0; j < 4; ++j) {
            size_t idx = (size_t)gr * ldc + tx * 4 + j;
            if (ACC) C[idx] += acc[i][j];
            else     C[idx] = acc[i][j];
        }
    }
}

// ---------- per-node attention scores (single head, C=64) ----------
__global__ __launch_bounds__(256) void attn1(const float* __restrict__ h,
                                             const float* __restrict__ avs,
                                             const float* __restrict__ avd,
                                             float* __restrict__ as_,
                                             float* __restrict__ ad_, int N) {
    int wave = (int)((blockIdx.x * 256llu + threadIdx.x) >> 6);
    int lane = threadIdx.x & 63;
    if (wave >= N) return;
    float v = h[(size_t)wave * 64 + lane];
    float ps = v * avs[lane], pd = v * avd[lane];
#pragma unroll
    for (int off = 32; off; off >>= 1) {
        ps += __shfl_xor(ps, off);
        pd += __shfl_xor(pd, off);
    }
    if (lane == 0) { as_[wave] = ps; ad_[wave] = pd; }
}

// ---------- edge pass A: segment-max of leaky_relu(as[src]+ad[dst]) ----------
__global__ __launch_bounds__(256) void edge_max1(const int* __restrict__ ei,
                                                 const float* __restrict__ as_,
                                                 const float* __restrict__ ad_,
                                                 unsigned* __restrict__ amax,
                                                 int E, int N) {
    int t = (int)(blockIdx.x * 256llu + threadIdx.x);
    if (t >= E + N) return;
    int src, dst;
    if (t < E) { src = ei[t]; dst = ei[E + t]; } else { src = dst = t - E; }
    float a = as_[src] + ad_[dst];
    a = a > 0.f ? a : 0.2f * a;
    atomicMax(amax + dst, enc_f32(a));
}

// ---------- edge pass B: w=exp(a-amax); denom[dst]+=w; out[dst]+=w*h[src] ----------
__global__ __launch_bounds__(256) void edge_agg1(const int* __restrict__ ei,
                                                 const float* __restrict__ as_,
                                                 const float* __restrict__ ad_,
                                                 const unsigned* __restrict__ amax,
                                                 const float* __restrict__ h,
                                                 float* __restrict__ outacc,
                                                 float* __restrict__ denom,
                                                 int E, int N) {
    int wave = (int)((blockIdx.x * 256llu + threadIdx.x) >> 6);
    int lane = threadIdx.x & 63;
    if (wave >= E + N) return;
    int src, dst;
    if (wave < E) { src = ei[wave]; dst = ei[E + wave]; } else { src = dst = wave - E; }
    float a = as_[src] + ad_[dst];
    a = a > 0.f ? a : 0.2f * a;
    float w = __expf(a - dec_f32(amax[dst]));
    if (lane == 0) atomicAdd(denom + dst, w);
    atomicAdd(outacc + (size_t)dst * 64 + lane, w * h[(size_t)src * 64 + lane]);
}

// ---------- finalize: io = relu(io/(denom+1e-16) + bias[c]) ----------
__global__ __launch_bounds__(256) void finalize1(float* __restrict__ io,
                                                 const float* __restrict__ denom,
                                                 const float* __restrict__ bias,
                                                 int N) {
    size_t i = blockIdx.x * 256llu + threadIdx.x;
    if (i >= (size_t)N * 64) return;
    int lane = (int)(i & 63);
    size_t n = i >> 6;
    float v = io[i] / (denom[n] + 1e-16f) + bias[lane];
    io[i] = v > 0.f ? v : 0.f;
}

// ---------- pooling ----------
__global__ __launch_bounds__(256) void pool_kernel(const float* __restrict__ h2,
                                                   const int* __restrict__ batch,
                                                   float* __restrict__ pooled,
                                                   float* __restrict__ cnt, int N) {
    int wave = (int)((blockIdx.x * 256llu + threadIdx.x) >> 6);
    int lane = threadIdx.x & 63;
    if (wave >= N) return;
    int b = batch[wave];
    atomicAdd(pooled + (size_t)b * 64 + lane, h2[(size_t)wave * 64 + lane]);
    if (lane == 0) atomicAdd(cnt + b, 1.0f);
}

// ---------- readout ----------
__global__ __launch_bounds__(256) void readout(const float* __restrict__ pooled,
                                               const float* __restrict__ cnt,
                                               const float* __restrict__ Wf,
                                               const float* __restrict__ bf,
                                               float* __restrict__ out, int G) {
    int g = (int)((blockIdx.x * 256llu + threadIdx.x) >> 6);
    int lane = threadIdx.x & 63;
    if (g >= G) return;
    float c = cnt[g];
    c = c < 1.f ? 1.f : c;
    float v = pooled[(size_t)g * 64 + lane] / c * Wf[lane];
#pragma unroll
    for (int off = 32; off; off >>= 1) v += __shfl_xor(v, off);
    if (lane == 0) out[g] = v + bf[0];
}

extern "C" void kernel_launch(void* const* d_in, const int* in_sizes, int n_in,
                              void* d_out, int out_size, void* d_ws, size_t ws_size,
                              hipStream_t stream) {
    const float* x        = (const float*)d_in[0];
    const int*   ei       = (const int*)d_in[1];
    const int*   batch    = (const int*)d_in[2];
    const float* W1       = (const float*)d_in[3];
    const float* att_src1 = (const float*)d_in[4];
    const float* att_dst1 = (const float*)d_in[5];
    const float* b1       = (const float*)d_in[6];
    const float* W2       = (const float*)d_in[7];
    const float* att_src2 = (const float*)d_in[8];
    const float* att_dst2 = (const float*)d_in[9];
    const float* b2       = (const float*)d_in[10];
    const float* Wf       = (const float*)d_in[11];
    const float* bf       = (const float*)d_in[12];
    float* out = (float*)d_out;

    const int N = in_sizes[2];        // 100000
    const int E = in_sizes[1] / 2;    // 400000
    const int G = out_size;           // 4096
    const int HEADS = 8, IN_DIM = 128, C = 64, D1 = 512;

    // ---- workspace layout (floats), total ~19.9M floats = ~80 MB ----
    float* ws = (float*)d_ws;
    size_t off = 0;
    float*    hb     = ws + off; off += (size_t)N * C;   // per-head h (layer1) / unused (layer2)
    float*    ob     = ws + off; off += (size_t)N * C;   // per-head out accumulator
    unsigned* amax   = (unsigned*)(ws + off); off += N;  // contiguous with ob for fused zeroing? (separate)
    float*    denom  = ws + off; off += N;
    float*    as_    = ws + off; off += N;
    float*    ad_    = ws + off; off += N;
    float*    h2acc  = ws + off; off += (size_t)N * C;   // layer-2 GEMM accumulator
    float*    pooled = ws + off; off += (size_t)G * C;
    float*    cnt    = ws + off; off += G;

    const int ZB = 2048;  // zero_fill grid
    const int nodeWaveGrid = (int)(((size_t)N * 64 + 255) / 256);
    const int edgeThreadGrid = (E + N + 255) / 256;
    const int edgeWaveGrid = (int)(((size_t)(E + N) * 64 + 255) / 256);
    const int gemmGrid = (N + 63) / 64;

    // zero the layer-2 accumulator once
    zero_fill<<<ZB, 256, 0, stream>>>(h2acc, (size_t)N * C);

    // ---- layer 1, streamed per head ----
    for (int h = 0; h < HEADS; ++h) {
        gemm64<false><<<gemmGrid, 256, 0, stream>>>(x, W1 + h * C, hb, N, IN_DIM, IN_DIM, D1, C);
        attn1<<<nodeWaveGrid, 256, 0, stream>>>(hb, att_src1 + h * C, att_dst1 + h * C, as_, ad_, N);
        // zero ob, amax, denom (ob and amax/denom are contiguous in the layout above)
        zero_fill<<<ZB, 256, 0, stream>>>(ob, (size_t)N * C + 2 * (size_t)N);
        edge_max1<<<edgeThreadGrid, 256, 0, stream>>>(ei, as_, ad_, amax, E, N);
        edge_agg1<<<edgeWaveGrid, 256, 0, stream>>>(ei, as_, ad_, amax, hb, ob, denom, E, N);
        finalize1<<<nodeWaveGrid, 256, 0, stream>>>(ob, denom, b1 + h * C, N);
        // h2acc += ob @ W2[h*64:(h+1)*64, :]
        gemm64<true><<<gemmGrid, 256, 0, stream>>>(ob, W2 + (size_t)h * C * C, h2acc, N, C, C, C, C);
    }

    // ---- layer 2 (single head) ----
    attn1<<<nodeWaveGrid, 256, 0, stream>>>(h2acc, att_src2, att_dst2, as_, ad_, N);
    zero_fill<<<ZB, 256, 0, stream>>>(ob, (size_t)N * C + 2 * (size_t)N);
    edge_max1<<<edgeThreadGrid, 256, 0, stream>>>(ei, as_, ad_, amax, E, N);
    edge_agg1<<<edgeWaveGrid, 256, 0, stream>>>(ei, as_, ad_, amax, h2acc, ob, denom, E, N);
    finalize1<<<nodeWaveGrid, 256, 0, stream>>>(ob, denom, b2, N);

    // ---- pooling + readout ----
    zero_fill<<<ZB, 256, 0, stream>>>(pooled, (size_t)G * C + G);
    pool_kernel<<<nodeWaveGrid, 256, 0, stream>>>(ob, batch, pooled, cnt, N);
    readout<<<(G * 64 + 255) / 256, 256, 0, stream>>>(pooled, cnt, Wf, bf, out, G);
}

// Round 3
// 1465.913 us; speedup vs baseline: 1.6611x; 1.6611x over previous
//
#include <hip/hip_runtime.h>

// ---------------- zero fill ----------------
__global__ __launch_bounds__(256) void zero_f32(float* __restrict__ p, size_t n) {
    size_t i = blockIdx.x * 256llu + threadIdx.x;
    size_t stride = (size_t)gridDim.x * 256llu;
    for (; i < n; i += stride) p[i] = 0.f;
}
__global__ __launch_bounds__(256) void zero_i32(int* __restrict__ p, int n) {
    int i = (int)(blockIdx.x * 256u + threadIdx.x);
    int stride = gridDim.x * 256;
    for (; i < n; i += stride) p[i] = 0;
}

// ---------------- CSR build ----------------
__global__ __launch_bounds__(256) void hist_kernel(const int* __restrict__ ei,
                                                   int* __restrict__ cnt, int E, int N) {
    int t = (int)(blockIdx.x * 256u + threadIdx.x);
    if (t >= E + N) return;
    int dst = (t < E) ? ei[E + t] : t - E;
    atomicAdd(cnt + dst, 1);
}

#define SCAN_BLK 2048
__global__ __launch_bounds__(256) void scan1(const int* __restrict__ cnt,
                                             int* __restrict__ rs,
                                             int* __restrict__ bsum, int N) {
    __shared__ int lds[256];
    int base = blockIdx.x * SCAN_BLK;
    int vals[8];
    int tsum = 0;
    int idx0 = base + threadIdx.x * 8;
#pragma unroll
    for (int j = 0; j < 8; ++j) {
        int i = idx0 + j;
        int v = (i < N) ? cnt[i] : 0;
        vals[j] = tsum;            // exclusive within thread
        tsum += v;
    }
    lds[threadIdx.x] = tsum;
    __syncthreads();
    for (int off = 1; off < 256; off <<= 1) {
        int v = lds[threadIdx.x];
        int u = (threadIdx.x >= (unsigned)off) ? lds[threadIdx.x - off] : 0;
        __syncthreads();
        lds[threadIdx.x] = v + u;
        __syncthreads();
    }
    int texcl = (threadIdx.x == 0) ? 0 : lds[threadIdx.x - 1];
#pragma unroll
    for (int j = 0; j < 8; ++j) {
        int i = idx0 + j;
        if (i < N) rs[i] = texcl + vals[j];
    }
    if (threadIdx.x == 255) bsum[blockIdx.x] = lds[255];
}

__global__ void scan2(int* __restrict__ bsum, int* __restrict__ rs, int nb, int N) {
    if (threadIdx.x == 0 && blockIdx.x == 0) {
        int run = 0;
        for (int b = 0; b < nb; ++b) { int t = bsum[b]; bsum[b] = run; run += t; }
        rs[N] = run;
    }
}

__global__ __launch_bounds__(256) void scan3(int* __restrict__ rs,
                                             const int* __restrict__ bsum, int N) {
    int i = (int)(blockIdx.x * 256u + threadIdx.x);
    if (i < N) rs[i] += bsum[i / SCAN_BLK];
}

__global__ __launch_bounds__(256) void scatter_kernel(const int* __restrict__ ei,
                                                      const int* __restrict__ rs,
                                                      int* __restrict__ cur,
                                                      int* __restrict__ csrc, int E, int N) {
    int t = (int)(blockIdx.x * 256u + threadIdx.x);
    if (t >= E + N) return;
    int src, dst;
    if (t < E) { src = ei[t]; dst = ei[E + t]; } else { src = dst = t - E; }
    int pos = rs[dst] + atomicAdd(cur + dst, 1);
    csrc[pos] = src;
}

// ---------------- GEMM: C[M,64] (+)= A[M,K] @ B[K,64], optional fused attn dots ----------------
template<bool ACC, bool ATTN>
__global__ __launch_bounds__(256) void gemm64(const float* __restrict__ A,
                                              const float* __restrict__ B,
                                              float* __restrict__ C,
                                              int M, int K, int lda, int ldb,
                                              const float* __restrict__ avs,
                                              const float* __restrict__ avd,
                                              float* __restrict__ as_,
                                              float* __restrict__ ad_) {
    const int BM = 64, BN = 64, BK = 32;
    __shared__ float As[BM][BK + 1];
    __shared__ float Bs[BK][BN + 1];
    const int tid = threadIdx.x;
    const int tx = tid & 15, ty = tid >> 4;
    const int row0 = blockIdx.x * BM;
    float acc[4][4] = {};
    for (int k0 = 0; k0 < K; k0 += BK) {
        for (int i = tid; i < BM * BK; i += 256) {
            int r = i >> 5, c = i & 31;
            int gr = row0 + r;
            As[r][c] = (gr < M) ? A[(size_t)gr * lda + k0 + c] : 0.f;
        }
        for (int i = tid; i < BK * BN; i += 256) {
            int r = i >> 6, c = i & 63;
            Bs[r][c] = B[(size_t)(k0 + r) * ldb + c];
        }
        __syncthreads();
#pragma unroll
        for (int k = 0; k < BK; ++k) {
            float a[4], b[4];
#pragma unroll
            for (int i = 0; i < 4; ++i) a[i] = As[ty * 4 + i][k];
#pragma unroll
            for (int j = 0; j < 4; ++j) b[j] = Bs[k][tx * 4 + j];
#pragma unroll
            for (int i = 0; i < 4; ++i)
#pragma unroll
                for (int j = 0; j < 4; ++j) acc[i][j] += a[i] * b[j];
        }
        __syncthreads();
    }
    float vloc[4][4];
#pragma unroll
    for (int i = 0; i < 4; ++i) {
        int gr = row0 + ty * 4 + i;
#pragma unroll
        for (int j = 0; j < 4; ++j) {
            float v = 0.f;
            if (gr < M) {
                size_t idx = (size_t)gr * 64 + tx * 4 + j;
                v = ACC ? (C[idx] + acc[i][j]) : acc[i][j];
                C[idx] = v;
            }
            vloc[i][j] = v;
        }
    }
    if (ATTN) {
        float* redS = &As[0][0];   // 64 x 16
        float* redD = &Bs[0][0];   // 64 x 16
#pragma unroll
        for (int i = 0; i < 4; ++i) {
            float ps = 0.f, pd = 0.f;
#pragma unroll
            for (int j = 0; j < 4; ++j) {
                ps += vloc[i][j] * avs[tx * 4 + j];
                pd += vloc[i][j] * avd[tx * 4 + j];
            }
            redS[(ty * 4 + i) * 16 + tx] = ps;
            redD[(ty * 4 + i) * 16 + tx] = pd;
        }
        __syncthreads();
        if (tid < 64) {
            float ss = 0.f, dd = 0.f;
#pragma unroll
            for (int t = 0; t < 16; ++t) { ss += redS[tid * 16 + t]; dd += redD[tid * 16 + t]; }
            int gr = row0 + tid;
            if (gr < M) { as_[gr] = ss; ad_[gr] = dd; }
        }
    }
}

// ---------------- fused gather: max + exp-agg + denom + bias + relu, one wave per dst ----------------
__global__ __launch_bounds__(256) void gat_gather(const int* __restrict__ csrc,
                                                  const int* __restrict__ rs,
                                                  const float* __restrict__ as_,
                                                  const float* __restrict__ ad_,
                                                  const float* __restrict__ h,
                                                  const float* __restrict__ bias,
                                                  float* __restrict__ outp, int N) {
    int node = (int)((blockIdx.x * 256u + threadIdx.x) >> 6);
    int lane = threadIdx.x & 63;
    if (node >= N) return;
    int s0 = rs[node], s1 = rs[node + 1];
    float adn = ad_[node];
    // pass 1: lane-parallel max
    float m = -3.4e38f;
    for (int k = s0 + lane; k < s1; k += 64) {
        float a = as_[csrc[k]] + adn;
        a = a > 0.f ? a : 0.2f * a;
        m = fmaxf(m, a);
    }
#pragma unroll
    for (int off = 32; off; off >>= 1) m = fmaxf(m, __shfl_xor(m, off));
    // pass 2: sequential weighted gather (csrc/as_ loads are wave-uniform -> broadcast)
    float den = 0.f, acc = 0.f;
    for (int k = s0; k < s1; ++k) {
        int src = csrc[k];
        float a = as_[src] + adn;
        a = a > 0.f ? a : 0.2f * a;
        float w = __expf(a - m);
        den += w;
        acc += w * h[(size_t)src * 64 + lane];
    }
    float v = acc / (den + 1e-16f) + bias[lane];
    outp[(size_t)node * 64 + lane] = v > 0.f ? v : 0.f;
}

// ---------------- pooling ----------------
__global__ __launch_bounds__(256) void pool_kernel(const float* __restrict__ h2,
                                                   const int* __restrict__ batch,
                                                   float* __restrict__ pooled,
                                                   float* __restrict__ cnt, int N) {
    int wave = (int)((blockIdx.x * 256u + threadIdx.x) >> 6);
    int lane = threadIdx.x & 63;
    if (wave >= N) return;
    int b = batch[wave];
    atomicAdd(pooled + (size_t)b * 64 + lane, h2[(size_t)wave * 64 + lane]);
    if (lane == 0) atomicAdd(cnt + b, 1.0f);
}

// ---------------- readout ----------------
__global__ __launch_bounds__(256) void readout(const float* __restrict__ pooled,
                                               const float* __restrict__ cnt,
                                               const float* __restrict__ Wf,
                                               const float* __restrict__ bf,
                                               float* __restrict__ out, int G) {
    int g = (int)((blockIdx.x * 256u + threadIdx.x) >> 6);
    int lane = threadIdx.x & 63;
    if (g >= G) return;
    float c = cnt[g];
    c = c < 1.f ? 1.f : c;
    float v = pooled[(size_t)g * 64 + lane] / c * Wf[lane];
#pragma unroll
    for (int off = 32; off; off >>= 1) v += __shfl_xor(v, off);
    if (lane == 0) out[g] = v + bf[0];
}

extern "C" void kernel_launch(void* const* d_in, const int* in_sizes, int n_in,
                              void* d_out, int out_size, void* d_ws, size_t ws_size,
                              hipStream_t stream) {
    const float* x        = (const float*)d_in[0];
    const int*   ei       = (const int*)d_in[1];
    const int*   batch    = (const int*)d_in[2];
    const float* W1       = (const float*)d_in[3];
    const float* att_src1 = (const float*)d_in[4];
    const float* att_dst1 = (const float*)d_in[5];
    const float* b1       = (const float*)d_in[6];
    const float* W2       = (const float*)d_in[7];
    const float* att_src2 = (const float*)d_in[8];
    const float* att_dst2 = (const float*)d_in[9];
    const float* b2       = (const float*)d_in[10];
    const float* Wf       = (const float*)d_in[11];
    const float* bf       = (const float*)d_in[12];
    float* out = (float*)d_out;

    const int N = in_sizes[2];        // 100000
    const int E = in_sizes[1] / 2;    // 400000
    const int G = out_size;           // 4096
    const int HEADS = 8, IN_DIM = 128, C = 64, D1 = 512;

    // ---- workspace layout ----
    float* ws = (float*)d_ws;
    float* hb     = ws;                         // N*64
    float* ob     = hb + (size_t)N * C;         // N*64
    float* h2acc  = ob + (size_t)N * C;         // N*64
    float* as_    = h2acc + (size_t)N * C;      // N
    float* ad_    = as_ + N;                    // N
    float* pooled = ad_ + N;                    // G*64
    float* cntG   = pooled + (size_t)G * C;     // G
    int*   cnt_i  = (int*)(cntG + G);           // N (histogram, then cursor)
    int*   rs     = cnt_i + N;                  // N+1
    int*   csrc   = rs + N + 1;                 // E+N
    int*   bsum   = csrc + (E + N);             // scan block sums

    const int nb = (N + SCAN_BLK - 1) / SCAN_BLK;
    const int nodeWaveGrid = (int)(((size_t)N * 64 + 255) / 256);
    const int edgeGrid = (E + N + 255) / 256;
    const int gemmGrid = (N + 63) / 64;

    // ---- CSR build ----
    zero_i32<<<512, 256, 0, stream>>>(cnt_i, N);
    hist_kernel<<<edgeGrid, 256, 0, stream>>>(ei, cnt_i, E, N);
    scan1<<<nb, 256, 0, stream>>>(cnt_i, rs, bsum, N);
    scan2<<<1, 1, 0, stream>>>(bsum, rs, nb, N);
    scan3<<<(N + 255) / 256, 256, 0, stream>>>(rs, bsum, N);
    zero_i32<<<512, 256, 0, stream>>>(cnt_i, N);
    scatter_kernel<<<edgeGrid, 256, 0, stream>>>(ei, rs, cnt_i, csrc, E, N);

    // ---- zero accumulators ----
    zero_f32<<<2048, 256, 0, stream>>>(h2acc, (size_t)N * C);
    zero_f32<<<512, 256, 0, stream>>>(pooled, (size_t)G * C + G);

    // ---- layer 1, streamed per head; layer-2 GEMM accumulated on the fly ----
    for (int h = 0; h < HEADS; ++h) {
        gemm64<false, true><<<gemmGrid, 256, 0, stream>>>(
            x, W1 + h * C, hb, N, IN_DIM, IN_DIM, D1,
            att_src1 + h * C, att_dst1 + h * C, as_, ad_);
        gat_gather<<<nodeWaveGrid, 256, 0, stream>>>(csrc, rs, as_, ad_, hb, b1 + h * C, ob, N);
        if (h == HEADS - 1) {
            // last head: fuse layer-2 attn dots on the final h2acc values
            gemm64<true, true><<<gemmGrid, 256, 0, stream>>>(
                ob, W2 + (size_t)h * C * C, h2acc, N, C, C, C,
                att_src2, att_dst2, as_, ad_);
        } else {
            gemm64<true, false><<<gemmGrid, 256, 0, stream>>>(
                ob, W2 + (size_t)h * C * C, h2acc, N, C, C, C,
                nullptr, nullptr, nullptr, nullptr);
        }
    }

    // ---- layer 2 aggregation ----
    gat_gather<<<nodeWaveGrid, 256, 0, stream>>>(csrc, rs, as_, ad_, h2acc, b2, ob, N);

    // ---- pooling + readout ----
    pool_kernel<<<nodeWaveGrid, 256, 0, stream>>>(ob, batch, pooled, cntG, N);
    readout<<<(G * 64 + 255) / 256, 256, 0, stream>>>(pooled, cntG, Wf, bf, out, G);
}

// Round 4
// 677.349 us; speedup vs baseline: 3.5949x; 2.1642x over previous
//
#include <hip/hip_runtime.h>

typedef short bfrag8 __attribute__((ext_vector_type(8)));
typedef float f32x4 __attribute__((ext_vector_type(4)));

// ---------- helpers ----------
__device__ __forceinline__ unsigned short f2bf(float f) {
    unsigned u = __float_as_uint(f);
    u += 0x7fffu + ((u >> 16) & 1u);   // round-to-nearest-even
    return (unsigned short)(u >> 16);
}
__device__ __forceinline__ float bf2f(unsigned short s) {
    return __uint_as_float((unsigned)s << 16);
}

// ---------- zero fill ----------
__global__ __launch_bounds__(256) void zero_f32(float* __restrict__ p, size_t n) {
    size_t i = blockIdx.x * 256llu + threadIdx.x;
    size_t stride = (size_t)gridDim.x * 256llu;
    for (; i < n; i += stride) p[i] = 0.f;
}
__global__ __launch_bounds__(256) void zero_i32(int* __restrict__ p, int n) {
    int i = (int)(blockIdx.x * 256u + threadIdx.x);
    int stride = gridDim.x * 256;
    for (; i < n; i += stride) p[i] = 0;
}

// ---------- conversions / weight packing ----------
__global__ __launch_bounds__(256) void cvt_f32_bf16(const float* __restrict__ in,
                                                    unsigned short* __restrict__ out, size_t n) {
    size_t i = (blockIdx.x * 256llu + threadIdx.x) * 4;
    size_t stride = (size_t)gridDim.x * 1024llu;
    for (; i < n; i += stride) {
        float4 v = *(const float4*)(in + i);
        out[i + 0] = f2bf(v.x);
        out[i + 1] = f2bf(v.y);
        out[i + 2] = f2bf(v.z);
        out[i + 3] = f2bf(v.w);
    }
}

// W1[128][512] -> frag-ready bf16: idx = (((h*4+s)*4+c)*64+l)*8+e
//   value = W1[s*32 + (l>>4)*8 + e][h*64 + c*16 + (l&15)]
__global__ __launch_bounds__(256) void prep_w1(const float* __restrict__ W1,
                                               unsigned short* __restrict__ out) {
    int i = (int)(blockIdx.x * 256u + threadIdx.x);
    if (i >= 8 * 4 * 4 * 64 * 8) return;
    int e = i & 7, l = (i >> 3) & 63, c = (i >> 9) & 3, s = (i >> 11) & 3, h = i >> 13;
    int k = s * 32 + (l >> 4) * 8 + e;
    int col = h * 64 + c * 16 + (l & 15);
    out[i] = f2bf(W1[k * 512 + col]);
}

// W2[512][64] -> frag-ready bf16: idx = (((h*2+s)*4+c)*64+l)*8+e
//   value = W2[h*64 + s*32 + (l>>4)*8 + e][c*16 + (l&15)]
__global__ __launch_bounds__(256) void prep_w2(const float* __restrict__ W2,
                                               unsigned short* __restrict__ out) {
    int i = (int)(blockIdx.x * 256u + threadIdx.x);
    if (i >= 8 * 2 * 4 * 64 * 8) return;
    int e = i & 7, l = (i >> 3) & 63, c = (i >> 9) & 3, s = (i >> 11) & 1, h = i >> 12;
    int k = h * 64 + s * 32 + (l >> 4) * 8 + e;
    int col = c * 16 + (l & 15);
    out[i] = f2bf(W2[k * 64 + col]);
}

// ---------- CSR build ----------
__global__ __launch_bounds__(256) void hist_kernel(const int* __restrict__ ei,
                                                   int* __restrict__ cnt, int E, int N) {
    int t = (int)(blockIdx.x * 256u + threadIdx.x);
    if (t >= E + N) return;
    int dst = (t < E) ? ei[E + t] : t - E;
    atomicAdd(cnt + dst, 1);
}

#define SCAN_BLK 2048
__global__ __launch_bounds__(256) void scan1(const int* __restrict__ cnt,
                                             int* __restrict__ rs,
                                             int* __restrict__ bsum, int N) {
    __shared__ int lds[256];
    int base = blockIdx.x * SCAN_BLK;
    int vals[8];
    int tsum = 0;
    int idx0 = base + threadIdx.x * 8;
#pragma unroll
    for (int j = 0; j < 8; ++j) {
        int i = idx0 + j;
        int v = (i < N) ? cnt[i] : 0;
        vals[j] = tsum;
        tsum += v;
    }
    lds[threadIdx.x] = tsum;
    __syncthreads();
    for (int off = 1; off < 256; off <<= 1) {
        int v = lds[threadIdx.x];
        int u = (threadIdx.x >= (unsigned)off) ? lds[threadIdx.x - off] : 0;
        __syncthreads();
        lds[threadIdx.x] = v + u;
        __syncthreads();
    }
    int texcl = (threadIdx.x == 0) ? 0 : lds[threadIdx.x - 1];
#pragma unroll
    for (int j = 0; j < 8; ++j) {
        int i = idx0 + j;
        if (i < N) rs[i] = texcl + vals[j];
    }
    if (threadIdx.x == 255) bsum[blockIdx.x] = lds[255];
}

__global__ void scan2(int* __restrict__ bsum, int* __restrict__ rs, int nb, int N) {
    if (threadIdx.x == 0 && blockIdx.x == 0) {
        int run = 0;
        for (int b = 0; b < nb; ++b) { int t = bsum[b]; bsum[b] = run; run += t; }
        rs[N] = run;
    }
}

__global__ __launch_bounds__(256) void scan3(int* __restrict__ rs,
                                             const int* __restrict__ bsum, int N) {
    int i = (int)(blockIdx.x * 256u + threadIdx.x);
    if (i < N) rs[i] += bsum[i / SCAN_BLK];
}

__global__ __launch_bounds__(256) void scatter_kernel(const int* __restrict__ ei,
                                                      const int* __restrict__ rs,
                                                      int* __restrict__ cur,
                                                      int* __restrict__ csrc, int E, int N) {
    int t = (int)(blockIdx.x * 256u + threadIdx.x);
    if (t >= E + N) return;
    int src, dst;
    if (t < E) { src = ei[t]; dst = ei[E + t]; } else { src = dst = t - E; }
    int pos = rs[dst] + atomicAdd(cur + dst, 1);
    csrc[pos] = src;
}

// ---------- MFMA GEMM: C[M,64] (+)= A[M,lda(bf16)] @ Bfrag, fused attn dots ----------
// Block: 256 thr = 4 waves, 128 rows. Wave: 32 rows x 64 cols via 2x4 16x16x32 frags.
template<int KS, bool ACC, bool WF32, bool WBF16, bool ATTN>
__global__ __launch_bounds__(256) void gemm_mfma(const unsigned short* __restrict__ A,
                                                 const unsigned short* __restrict__ Bfrag,
                                                 float* __restrict__ Cf32,
                                                 unsigned short* __restrict__ Cbf,
                                                 int M, int lda,
                                                 const float* __restrict__ avs,
                                                 const float* __restrict__ avd,
                                                 float* __restrict__ as_,
                                                 float* __restrict__ ad_) {
    const int lane = threadIdx.x & 63;
    const int wave = threadIdx.x >> 6;
    const int l15 = lane & 15, l16 = lane >> 4;
    const long rowBase = (long)blockIdx.x * 128 + wave * 32;

    bfrag8 bf[KS][4];
    const bfrag8* bp = (const bfrag8*)Bfrag;
#pragma unroll
    for (int s = 0; s < KS; ++s)
#pragma unroll
        for (int c = 0; c < 4; ++c)
            bf[s][c] = bp[(s * 4 + c) * 64 + lane];

    f32x4 acc[2][4];
#pragma unroll
    for (int r = 0; r < 2; ++r)
#pragma unroll
        for (int c = 0; c < 4; ++c)
#pragma unroll
            for (int e = 0; e < 4; ++e) acc[r][c][e] = 0.f;

    long r0 = rowBase + l15;        if (r0 > M - 1) r0 = M - 1;
    long r1 = rowBase + 16 + l15;   if (r1 > M - 1) r1 = M - 1;
    const unsigned short* a0p = A + r0 * lda + l16 * 8;
    const unsigned short* a1p = A + r1 * lda + l16 * 8;

#pragma unroll
    for (int s = 0; s < KS; ++s) {
        bfrag8 a0 = *(const bfrag8*)(a0p + s * 32);
        bfrag8 a1 = *(const bfrag8*)(a1p + s * 32);
#pragma unroll
        for (int c = 0; c < 4; ++c) {
            acc[0][c] = __builtin_amdgcn_mfma_f32_16x16x32_bf16(a0, bf[s][c], acc[0][c], 0, 0, 0);
            acc[1][c] = __builtin_amdgcn_mfma_f32_16x16x32_bf16(a1, bf[s][c], acc[1][c], 0, 0, 0);
        }
    }

    float avsv[4], avdv[4];
    if (ATTN) {
#pragma unroll
        for (int c = 0; c < 4; ++c) {
            avsv[c] = avs[c * 16 + l15];
            avdv[c] = avd[c * 16 + l15];
        }
    }

#pragma unroll
    for (int r = 0; r < 2; ++r) {
#pragma unroll
        for (int reg = 0; reg < 4; ++reg) {
            long row = rowBase + r * 16 + l16 * 4 + reg;
            bool ok = row < M;
            float ps = 0.f, pd = 0.f;
#pragma unroll
            for (int c = 0; c < 4; ++c) {
                float v = acc[r][c][reg];
                long idx = row * 64 + c * 16 + l15;
                if (ACC && ok) v += Cf32[idx];
                if (WF32 && ok) Cf32[idx] = v;
                if (WBF16 && ok) Cbf[idx] = f2bf(v);
                if (ATTN) { ps += v * avsv[c]; pd += v * avdv[c]; }
            }
            if (ATTN) {
#pragma unroll
                for (int off = 1; off < 16; off <<= 1) {
                    ps += __shfl_xor(ps, off);
                    pd += __shfl_xor(pd, off);
                }
                if (l15 == 0 && ok) { as_[row] = ps; ad_[row] = pd; }
            }
        }
    }
}

// ---------- fused gather: single-pass (no max shift), unroll-4, bf16 h ----------
template<bool OBF>
__global__ __launch_bounds__(256) void gat_gather(const int* __restrict__ csrc,
                                                  const int* __restrict__ rs,
                                                  const float* __restrict__ as_,
                                                  const float* __restrict__ ad_,
                                                  const unsigned short* __restrict__ h,
                                                  const float* __restrict__ bias,
                                                  void* __restrict__ outp, int N) {
    int node = (int)((blockIdx.x * 256u + threadIdx.x) >> 6);
    int lane = threadIdx.x & 63;
    if (node >= N) return;
    int s0 = rs[node], s1 = rs[node + 1];
    float adn = ad_[node];
    float den = 0.f, acc = 0.f;
    int k = s0;
    for (; k + 4 <= s1; k += 4) {
        int i0 = csrc[k], i1 = csrc[k + 1], i2 = csrc[k + 2], i3 = csrc[k + 3];
        float a0 = as_[i0] + adn, a1 = as_[i1] + adn, a2 = as_[i2] + adn, a3 = as_[i3] + adn;
        a0 = a0 > 0.f ? a0 : 0.2f * a0;  a1 = a1 > 0.f ? a1 : 0.2f * a1;
        a2 = a2 > 0.f ? a2 : 0.2f * a2;  a3 = a3 > 0.f ? a3 : 0.2f * a3;
        float w0 = __expf(fminf(a0, 60.f)), w1 = __expf(fminf(a1, 60.f));
        float w2 = __expf(fminf(a2, 60.f)), w3 = __expf(fminf(a3, 60.f));
        float h0 = bf2f(h[(size_t)i0 * 64 + lane]);
        float h1 = bf2f(h[(size_t)i1 * 64 + lane]);
        float h2 = bf2f(h[(size_t)i2 * 64 + lane]);
        float h3 = bf2f(h[(size_t)i3 * 64 + lane]);
        den += (w0 + w1) + (w2 + w3);
        acc += w0 * h0;  acc += w1 * h1;  acc += w2 * h2;  acc += w3 * h3;
    }
    for (; k < s1; ++k) {
        int i0 = csrc[k];
        float a = as_[i0] + adn;
        a = a > 0.f ? a : 0.2f * a;
        float w = __expf(fminf(a, 60.f));
        den += w;
        acc += w * bf2f(h[(size_t)i0 * 64 + lane]);
    }
    float v = acc / (den + 1e-16f) + bias[lane];
    v = v > 0.f ? v : 0.f;
    if (OBF) ((unsigned short*)outp)[(size_t)node * 64 + lane] = f2bf(v);
    else     ((float*)outp)[(size_t)node * 64 + lane] = v;
}

// ---------- pooling ----------
__global__ __launch_bounds__(256) void pool_kernel(const float* __restrict__ h2,
                                                   const int* __restrict__ batch,
                                                   float* __restrict__ pooled,
                                                   float* __restrict__ cnt, int N) {
    int wave = (int)((blockIdx.x * 256u + threadIdx.x) >> 6);
    int lane = threadIdx.x & 63;
    if (wave >= N) return;
    int b = batch[wave];
    atomicAdd(pooled + (size_t)b * 64 + lane, h2[(size_t)wave * 64 + lane]);
    if (lane == 0) atomicAdd(cnt + b, 1.0f);
}

// ---------- readout ----------
__global__ __launch_bounds__(256) void readout(const float* __restrict__ pooled,
                                               const float* __restrict__ cnt,
                                               const float* __restrict__ Wf,
                                               const float* __restrict__ bf,
                                               float* __restrict__ out, int G) {
    int g = (int)((blockIdx.x * 256u + threadIdx.x) >> 6);
    int lane = threadIdx.x & 63;
    if (g >= G) return;
    float c = cnt[g];
    c = c < 1.f ? 1.f : c;
    float v = pooled[(size_t)g * 64 + lane] / c * Wf[lane];
#pragma unroll
    for (int off = 32; off; off >>= 1) v += __shfl_xor(v, off);
    if (lane == 0) out[g] = v + bf[0];
}

extern "C" void kernel_launch(void* const* d_in, const int* in_sizes, int n_in,
                              void* d_out, int out_size, void* d_ws, size_t ws_size,
                              hipStream_t stream) {
    const float* x        = (const float*)d_in[0];
    const int*   ei       = (const int*)d_in[1];
    const int*   batch    = (const int*)d_in[2];
    const float* W1       = (const float*)d_in[3];
    const float* att_src1 = (const float*)d_in[4];
    const float* att_dst1 = (const float*)d_in[5];
    const float* b1       = (const float*)d_in[6];
    const float* W2       = (const float*)d_in[7];
    const float* att_src2 = (const float*)d_in[8];
    const float* att_dst2 = (const float*)d_in[9];
    const float* b2       = (const float*)d_in[10];
    const float* Wf       = (const float*)d_in[11];
    const float* bf       = (const float*)d_in[12];
    float* out = (float*)d_out;

    const int N = in_sizes[2];        // 100000
    const int E = in_sizes[1] / 2;    // 400000
    const int G = out_size;           // 4096

    // ---- workspace layout (float granularity) ----
    float* ws = (float*)d_ws;
    size_t off = 0;
    unsigned short* x_bf  = (unsigned short*)(ws + off);  // N*128 bf16
    float*          ob2   = ws + off;                     // alias: N*64 f32 (after layer 1)
    off += (size_t)N * 64;
    unsigned short* hb_bf = (unsigned short*)(ws + off);  // N*64 bf16 (per-head h)
    unsigned short* h2bf  = hb_bf;                        // alias (after last L1 gather)
    off += (size_t)N * 32;
    unsigned short* ob_bf = (unsigned short*)(ws + off);  // N*64 bf16 (per-head out)
    off += (size_t)N * 32;
    float* h2acc  = ws + off; off += (size_t)N * 64;      // layer-2 fp32 accumulator
    float* as_    = ws + off; off += N;
    float* ad_    = ws + off; off += N;
    float* pooled = ws + off; off += (size_t)G * 64;
    float* cntG   = ws + off; off += G;
    int* cnt_i = (int*)(ws + off); off += N;
    int* rs    = (int*)(ws + off); off += N + 1;
    int* csrc  = (int*)(ws + off); off += E + N;
    int* bsum  = (int*)(ws + off); off += 64;
    unsigned short* wf1 = (unsigned short*)(ws + off); off += 32768;  // 8*4*4*64*8 bf16
    unsigned short* wf2 = (unsigned short*)(ws + off); off += 16384;  // 8*2*4*64*8 bf16

    const int nb = (N + SCAN_BLK - 1) / SCAN_BLK;
    const int nodeWaveGrid = (int)(((size_t)N * 64 + 255) / 256);
    const int edgeGrid = (E + N + 255) / 256;
    const int gemmGrid = (N + 127) / 128;

    // ---- conversions / packing ----
    cvt_f32_bf16<<<2048, 256, 0, stream>>>(x, x_bf, (size_t)N * 128);
    prep_w1<<<(8 * 4 * 4 * 64 * 8) / 256, 256, 0, stream>>>(W1, wf1);
    prep_w2<<<(8 * 2 * 4 * 64 * 8) / 256, 256, 0, stream>>>(W2, wf2);

    // ---- CSR build ----
    zero_i32<<<512, 256, 0, stream>>>(cnt_i, N);
    hist_kernel<<<edgeGrid, 256, 0, stream>>>(ei, cnt_i, E, N);
    scan1<<<nb, 256, 0, stream>>>(cnt_i, rs, bsum, N);
    scan2<<<1, 1, 0, stream>>>(bsum, rs, nb, N);
    scan3<<<(N + 255) / 256, 256, 0, stream>>>(rs, bsum, N);
    zero_i32<<<512, 256, 0, stream>>>(cnt_i, N);
    scatter_kernel<<<edgeGrid, 256, 0, stream>>>(ei, rs, cnt_i, csrc, E, N);

    zero_f32<<<512, 256, 0, stream>>>(pooled, (size_t)G * 64 + G);

    // ---- layer 1 per head, layer-2 GEMM accumulated on the fly ----
    for (int h = 0; h < 8; ++h) {
        gemm_mfma<4, false, false, true, true><<<gemmGrid, 256, 0, stream>>>(
            x_bf, wf1 + (size_t)h * 8192, nullptr, hb_bf, N, 128,
            att_src1 + h * 64, att_dst1 + h * 64, as_, ad_);
        gat_gather<true><<<nodeWaveGrid, 256, 0, stream>>>(
            csrc, rs, as_, ad_, hb_bf, b1 + h * 64, ob_bf, N);
        if (h == 0) {
            gemm_mfma<2, false, true, false, false><<<gemmGrid, 256, 0, stream>>>(
                ob_bf, wf2, h2acc, nullptr, N, 64, nullptr, nullptr, nullptr, nullptr);
        } else if (h < 7) {
            gemm_mfma<2, true, true, false, false><<<gemmGrid, 256, 0, stream>>>(
                ob_bf, wf2 + (size_t)h * 4096, h2acc, nullptr, N, 64, nullptr, nullptr, nullptr, nullptr);
        } else {
            gemm_mfma<2, true, false, true, true><<<gemmGrid, 256, 0, stream>>>(
                ob_bf, wf2 + (size_t)h * 4096, h2acc, h2bf, N, 64,
                att_src2, att_dst2, as_, ad_);
        }
    }

    // ---- layer 2 aggregation ----
    gat_gather<false><<<nodeWaveGrid, 256, 0, stream>>>(
        csrc, rs, as_, ad_, h2bf, b2, ob2, N);

    // ---- pooling + readout ----
    pool_kernel<<<nodeWaveGrid, 256, 0, stream>>>(ob2, batch, pooled, cntG, N);
    readout<<<(G * 64 + 255) / 256, 256, 0, stream>>>(pooled, cntG, Wf, bf, out, G);
}

// Round 5
// 313.173 us; speedup vs baseline: 7.7753x; 2.1629x over previous
//
#include <hip/hip_runtime.h>

typedef short bfrag8 __attribute__((ext_vector_type(8)));
typedef float f32x4 __attribute__((ext_vector_type(4)));

// ---------- helpers ----------
__device__ __forceinline__ unsigned short f2bf(float f) {
    unsigned u = __float_as_uint(f);
    u += 0x7fffu + ((u >> 16) & 1u);   // round-to-nearest-even
    return (unsigned short)(u >> 16);
}
__device__ __forceinline__ float bf2f(unsigned short s) {
    return __uint_as_float((unsigned)s << 16);
}

// ---------- zero fill ----------
__global__ __launch_bounds__(256) void zero_i32(int* __restrict__ p, int n) {
    int i = (int)(blockIdx.x * 256u + threadIdx.x);
    int stride = gridDim.x * 256;
    for (; i < n; i += stride) p[i] = 0;
}

// ---------- conversions / weight packing ----------
__global__ __launch_bounds__(256) void cvt_f32_bf16(const float* __restrict__ in,
                                                    unsigned short* __restrict__ out, size_t n) {
    size_t i = (blockIdx.x * 256llu + threadIdx.x) * 4;
    size_t stride = (size_t)gridDim.x * 1024llu;
    for (; i < n; i += stride) {
        float4 v = *(const float4*)(in + i);
        out[i + 0] = f2bf(v.x);
        out[i + 1] = f2bf(v.y);
        out[i + 2] = f2bf(v.z);
        out[i + 3] = f2bf(v.w);
    }
}

// W1[128][512] -> frag-ready bf16: idx = (((h*4+s)*4+c)*64+l)*8+e
//   value = W1[s*32 + (l>>4)*8 + e][h*64 + c*16 + (l&15)]
__global__ __launch_bounds__(256) void prep_w1(const float* __restrict__ W1,
                                               unsigned short* __restrict__ out) {
    int i = (int)(blockIdx.x * 256u + threadIdx.x);
    if (i >= 8 * 4 * 4 * 64 * 8) return;
    int e = i & 7, l = (i >> 3) & 63, c = (i >> 9) & 3, s = (i >> 11) & 3, h = i >> 13;
    int k = s * 32 + (l >> 4) * 8 + e;
    int col = h * 64 + c * 16 + (l & 15);
    out[i] = f2bf(W1[k * 512 + col]);
}

// W2[512][64] -> frag-ready bf16: idx = ((s*4+c)*64+l)*8+e  (s = 0..15)
//   value = W2[s*32 + (l>>4)*8 + e][c*16 + (l&15)]
__global__ __launch_bounds__(256) void prep_w2(const float* __restrict__ W2,
                                               unsigned short* __restrict__ out) {
    int i = (int)(blockIdx.x * 256u + threadIdx.x);
    if (i >= 16 * 4 * 64 * 8) return;
    int e = i & 7, l = (i >> 3) & 63, c = (i >> 9) & 3, s = i >> 11;
    int k = s * 32 + (l >> 4) * 8 + e;
    int col = c * 16 + (l & 15);
    out[i] = f2bf(W2[k * 64 + col]);
}

// ---------- CSR build ----------
__global__ __launch_bounds__(256) void hist_kernel(const int* __restrict__ ei,
                                                   int* __restrict__ cnt, int E, int N) {
    int t = (int)(blockIdx.x * 256u + threadIdx.x);
    if (t >= E + N) return;
    int dst = (t < E) ? ei[E + t] : t - E;
    atomicAdd(cnt + dst, 1);
}

#define SCAN_BLK 2048
__global__ __launch_bounds__(256) void scan1(const int* __restrict__ cnt,
                                             int* __restrict__ rs,
                                             int* __restrict__ bsum, int N) {
    __shared__ int lds[256];
    int base = blockIdx.x * SCAN_BLK;
    int vals[8];
    int tsum = 0;
    int idx0 = base + threadIdx.x * 8;
#pragma unroll
    for (int j = 0; j < 8; ++j) {
        int i = idx0 + j;
        int v = (i < N) ? cnt[i] : 0;
        vals[j] = tsum;
        tsum += v;
    }
    lds[threadIdx.x] = tsum;
    __syncthreads();
    for (int off = 1; off < 256; off <<= 1) {
        int v = lds[threadIdx.x];
        int u = (threadIdx.x >= (unsigned)off) ? lds[threadIdx.x - off] : 0;
        __syncthreads();
        lds[threadIdx.x] = v + u;
        __syncthreads();
    }
    int texcl = (threadIdx.x == 0) ? 0 : lds[threadIdx.x - 1];
#pragma unroll
    for (int j = 0; j < 8; ++j) {
        int i = idx0 + j;
        if (i < N) rs[i] = texcl + vals[j];
    }
    if (threadIdx.x == 255) bsum[blockIdx.x] = lds[255];
}

__global__ void scan2(int* __restrict__ bsum, int* __restrict__ rs, int nb, int N) {
    if (threadIdx.x == 0 && blockIdx.x == 0) {
        int run = 0;
        for (int b = 0; b < nb; ++b) { int t = bsum[b]; bsum[b] = run; run += t; }
        rs[N] = run;
    }
}

__global__ __launch_bounds__(256) void scan3(int* __restrict__ rs,
                                             const int* __restrict__ bsum, int N) {
    int i = (int)(blockIdx.x * 256u + threadIdx.x);
    if (i < N) rs[i] += bsum[i / SCAN_BLK];
}

__global__ __launch_bounds__(256) void scatter_kernel(const int* __restrict__ ei,
                                                      const int* __restrict__ rs,
                                                      int* __restrict__ cur,
                                                      int* __restrict__ csrc, int E, int N) {
    int t = (int)(blockIdx.x * 256u + threadIdx.x);
    if (t >= E + N) return;
    int src, dst;
    if (t < E) { src = ei[t]; dst = ei[E + t]; } else { src = dst = t - E; }
    int pos = rs[dst] + atomicAdd(cur + dst, 1);
    csrc[pos] = src;
}

// ---------- graph-range build (batch is sorted) ----------
__global__ __launch_bounds__(256) void gstart_build(const int* __restrict__ batch,
                                                    int* __restrict__ gstart, int N, int G) {
    int i = (int)(blockIdx.x * 256u + threadIdx.x);
    if (i > N) return;
    if (i == N) {
        int p = batch[N - 1];
        for (int g = p + 1; g <= G; ++g) gstart[g] = N;
    } else {
        int b = batch[i];
        int p = (i == 0) ? -1 : batch[i - 1];
        for (int g = p + 1; g <= b; ++g) gstart[g] = i;
    }
}

// ---------- MFMA GEMM L1: Cbf[M,ldc] cols [cb*64, cb*64+64) = A[M,128] @ Bfrag[cb] ----------
// grid.y = col-blocks (heads). Fused attn dots -> as_[row*asStride + cb].
__global__ __launch_bounds__(256) void gemm_l1(const unsigned short* __restrict__ A,
                                               const unsigned short* __restrict__ Bfrag,
                                               unsigned short* __restrict__ Cbf,
                                               int M, int ldc, int asStride,
                                               const float* __restrict__ avs,
                                               const float* __restrict__ avd,
                                               float* __restrict__ as_,
                                               float* __restrict__ ad_) {
    const int lane = threadIdx.x & 63;
    const int wave = threadIdx.x >> 6;
    const int l15 = lane & 15, l16 = lane >> 4;
    const int cb = blockIdx.y;
    const long rowBase = (long)blockIdx.x * 128 + wave * 32;

    bfrag8 bf[4][4];
    const bfrag8* bp = (const bfrag8*)(Bfrag + (size_t)cb * 8192);
#pragma unroll
    for (int s = 0; s < 4; ++s)
#pragma unroll
        for (int c = 0; c < 4; ++c)
            bf[s][c] = bp[(s * 4 + c) * 64 + lane];

    f32x4 acc[2][4];
#pragma unroll
    for (int r = 0; r < 2; ++r)
#pragma unroll
        for (int c = 0; c < 4; ++c)
#pragma unroll
            for (int e = 0; e < 4; ++e) acc[r][c][e] = 0.f;

    long r0 = rowBase + l15;        if (r0 > M - 1) r0 = M - 1;
    long r1 = rowBase + 16 + l15;   if (r1 > M - 1) r1 = M - 1;
    const unsigned short* a0p = A + r0 * 128 + l16 * 8;
    const unsigned short* a1p = A + r1 * 128 + l16 * 8;

#pragma unroll
    for (int s = 0; s < 4; ++s) {
        bfrag8 a0 = *(const bfrag8*)(a0p + s * 32);
        bfrag8 a1 = *(const bfrag8*)(a1p + s * 32);
#pragma unroll
        for (int c = 0; c < 4; ++c) {
            acc[0][c] = __builtin_amdgcn_mfma_f32_16x16x32_bf16(a0, bf[s][c], acc[0][c], 0, 0, 0);
            acc[1][c] = __builtin_amdgcn_mfma_f32_16x16x32_bf16(a1, bf[s][c], acc[1][c], 0, 0, 0);
        }
    }

    float avsv[4], avdv[4];
#pragma unroll
    for (int c = 0; c < 4; ++c) {
        avsv[c] = avs[cb * 64 + c * 16 + l15];
        avdv[c] = avd[cb * 64 + c * 16 + l15];
    }

#pragma unroll
    for (int r = 0; r < 2; ++r) {
#pragma unroll
        for (int reg = 0; reg < 4; ++reg) {
            long row = rowBase + r * 16 + l16 * 4 + reg;
            bool ok = row < M;
            float ps = 0.f, pd = 0.f;
#pragma unroll
            for (int c = 0; c < 4; ++c) {
                float v = acc[r][c][reg];
                if (ok) Cbf[row * ldc + cb * 64 + c * 16 + l15] = f2bf(v);
                ps += v * avsv[c];
                pd += v * avdv[c];
            }
#pragma unroll
            for (int off = 1; off < 16; off <<= 1) {
                ps += __shfl_xor(ps, off);
                pd += __shfl_xor(pd, off);
            }
            if (l15 == 0 && ok) {
                as_[row * asStride + cb] = ps;
                ad_[row * asStride + cb] = pd;
            }
        }
    }
}

// ---------- MFMA GEMM L2: h2bf[M,64] = A[M,512] @ Bfrag(K=512), fused attn dots ----------
__global__ __launch_bounds__(256) void gemm_l2_k512(const unsigned short* __restrict__ A,
                                                    const unsigned short* __restrict__ Bfrag,
                                                    unsigned short* __restrict__ Cbf,
                                                    int M,
                                                    const float* __restrict__ avs,
                                                    const float* __restrict__ avd,
                                                    float* __restrict__ as_,
                                                    float* __restrict__ ad_) {
    const int lane = threadIdx.x & 63;
    const int wave = threadIdx.x >> 6;
    const int l15 = lane & 15, l16 = lane >> 4;
    const long rowBase = (long)blockIdx.x * 128 + wave * 32;
    const bfrag8* bp = (const bfrag8*)Bfrag;

    f32x4 acc[2][4];
#pragma unroll
    for (int r = 0; r < 2; ++r)
#pragma unroll
        for (int c = 0; c < 4; ++c)
#pragma unroll
            for (int e = 0; e < 4; ++e) acc[r][c][e] = 0.f;

    long r0 = rowBase + l15;        if (r0 > M - 1) r0 = M - 1;
    long r1 = rowBase + 16 + l15;   if (r1 > M - 1) r1 = M - 1;
    const unsigned short* a0p = A + r0 * 512 + l16 * 8;
    const unsigned short* a1p = A + r1 * 512 + l16 * 8;

    for (int s = 0; s < 16; ++s) {
        bfrag8 a0 = *(const bfrag8*)(a0p + s * 32);
        bfrag8 a1 = *(const bfrag8*)(a1p + s * 32);
        bfrag8 bf0 = bp[(s * 4 + 0) * 64 + lane];
        bfrag8 bf1 = bp[(s * 4 + 1) * 64 + lane];
        bfrag8 bf2 = bp[(s * 4 + 2) * 64 + lane];
        bfrag8 bf3 = bp[(s * 4 + 3) * 64 + lane];
        acc[0][0] = __builtin_amdgcn_mfma_f32_16x16x32_bf16(a0, bf0, acc[0][0], 0, 0, 0);
        acc[1][0] = __builtin_amdgcn_mfma_f32_16x16x32_bf16(a1, bf0, acc[1][0], 0, 0, 0);
        acc[0][1] = __builtin_amdgcn_mfma_f32_16x16x32_bf16(a0, bf1, acc[0][1], 0, 0, 0);
        acc[1][1] = __builtin_amdgcn_mfma_f32_16x16x32_bf16(a1, bf1, acc[1][1], 0, 0, 0);
        acc[0][2] = __builtin_amdgcn_mfma_f32_16x16x32_bf16(a0, bf2, acc[0][2], 0, 0, 0);
        acc[1][2] = __builtin_amdgcn_mfma_f32_16x16x32_bf16(a1, bf2, acc[1][2], 0, 0, 0);
        acc[0][3] = __builtin_amdgcn_mfma_f32_16x16x32_bf16(a0, bf3, acc[0][3], 0, 0, 0);
        acc[1][3] = __builtin_amdgcn_mfma_f32_16x16x32_bf16(a1, bf3, acc[1][3], 0, 0, 0);
    }

    float avsv[4], avdv[4];
#pragma unroll
    for (int c = 0; c < 4; ++c) {
        avsv[c] = avs[c * 16 + l15];
        avdv[c] = avd[c * 16 + l15];
    }

#pragma unroll
    for (int r = 0; r < 2; ++r) {
#pragma unroll
        for (int reg = 0; reg < 4; ++reg) {
            long row = rowBase + r * 16 + l16 * 4 + reg;
            bool ok = row < M;
            float ps = 0.f, pd = 0.f;
#pragma unroll
            for (int c = 0; c < 4; ++c) {
                float v = acc[r][c][reg];
                if (ok) Cbf[row * 64 + c * 16 + l15] = f2bf(v);
                ps += v * avsv[c];
                pd += v * avdv[c];
            }
#pragma unroll
            for (int off = 1; off < 16; off <<= 1) {
                ps += __shfl_xor(ps, off);
                pd += __shfl_xor(pd, off);
            }
            if (l15 == 0 && ok) { as_[row] = ps; ad_[row] = pd; }
        }
    }
}

// ---------- old-style accumulate GEMM (fallback path, KS=2, C64) ----------
template<bool ACC, bool WF32, bool WBF16, bool ATTN>
__global__ __launch_bounds__(256) void gemm_acc(const unsigned short* __restrict__ A,
                                                const unsigned short* __restrict__ Bfrag,
                                                float* __restrict__ Cf32,
                                                unsigned short* __restrict__ Cbf,
                                                int M,
                                                const float* __restrict__ avs,
                                                const float* __restrict__ avd,
                                                float* __restrict__ as_,
                                                float* __restrict__ ad_) {
    const int lane = threadIdx.x & 63;
    const int wave = threadIdx.x >> 6;
    const int l15 = lane & 15, l16 = lane >> 4;
    const long rowBase = (long)blockIdx.x * 128 + wave * 32;

    bfrag8 bf[2][4];
    const bfrag8* bp = (const bfrag8*)Bfrag;
#pragma unroll
    for (int s = 0; s < 2; ++s)
#pragma unroll
        for (int c = 0; c < 4; ++c)
            bf[s][c] = bp[(s * 4 + c) * 64 + lane];

    f32x4 acc[2][4];
#pragma unroll
    for (int r = 0; r < 2; ++r)
#pragma unroll
        for (int c = 0; c < 4; ++c)
#pragma unroll
            for (int e = 0; e < 4; ++e) acc[r][c][e] = 0.f;

    long r0 = rowBase + l15;        if (r0 > M - 1) r0 = M - 1;
    long r1 = rowBase + 16 + l15;   if (r1 > M - 1) r1 = M - 1;
    const unsigned short* a0p = A + r0 * 64 + l16 * 8;
    const unsigned short* a1p = A + r1 * 64 + l16 * 8;

#pragma unroll
    for (int s = 0; s < 2; ++s) {
        bfrag8 a0 = *(const bfrag8*)(a0p + s * 32);
        bfrag8 a1 = *(const bfrag8*)(a1p + s * 32);
#pragma unroll
        for (int c = 0; c < 4; ++c) {
            acc[0][c] = __builtin_amdgcn_mfma_f32_16x16x32_bf16(a0, bf[s][c], acc[0][c], 0, 0, 0);
            acc[1][c] = __builtin_amdgcn_mfma_f32_16x16x32_bf16(a1, bf[s][c], acc[1][c], 0, 0, 0);
        }
    }

    float avsv[4], avdv[4];
    if (ATTN) {
#pragma unroll
        for (int c = 0; c < 4; ++c) {
            avsv[c] = avs[c * 16 + l15];
            avdv[c] = avd[c * 16 + l15];
        }
    }

#pragma unroll
    for (int r = 0; r < 2; ++r) {
#pragma unroll
        for (int reg = 0; reg < 4; ++reg) {
            long row = rowBase + r * 16 + l16 * 4 + reg;
            bool ok = row < M;
            float ps = 0.f, pd = 0.f;
#pragma unroll
            for (int c = 0; c < 4; ++c) {
                float v = acc[r][c][reg];
                long idx = row * 64 + c * 16 + l15;
                if (ACC && ok) v += Cf32[idx];
                if (WF32 && ok) Cf32[idx] = v;
                if (WBF16 && ok) Cbf[idx] = f2bf(v);
                if (ATTN) { ps += v * avsv[c]; pd += v * avdv[c]; }
            }
            if (ATTN) {
#pragma unroll
                for (int off = 1; off < 16; off <<= 1) {
                    ps += __shfl_xor(ps, off);
                    pd += __shfl_xor(pd, off);
                }
                if (l15 == 0 && ok) { as_[row] = ps; ad_[row] = pd; }
            }
        }
    }
}

// ---------- gather over all 8 heads: lane l owns cols [8l, 8l+8) of 512 ----------
__global__ __launch_bounds__(256) void gather8(const int* __restrict__ csrc,
                                               const int* __restrict__ rs,
                                               const float* __restrict__ as_,  // [N][8]
                                               const float* __restrict__ ad_,  // [N][8]
                                               const unsigned short* __restrict__ h, // [N][512]
                                               const float* __restrict__ bias,      // [512]
                                               unsigned short* __restrict__ outp,   // [N][512]
                                               int N) {
    int node = (int)((blockIdx.x * 256u + threadIdx.x) >> 6);
    int lane = threadIdx.x & 63;
    if (node >= N) return;
    int myh = lane >> 3;
    int s0 = rs[node], s1 = rs[node + 1];
    float adn = ad_[(size_t)node * 8 + myh];
    float den = 0.f;
    float acc[8] = {};
    int k = s0;
    for (; k + 2 <= s1; k += 2) {
        int i0 = csrc[k], i1 = csrc[k + 1];
        float a0 = as_[(size_t)i0 * 8 + myh] + adn;
        float a1 = as_[(size_t)i1 * 8 + myh] + adn;
        a0 = a0 > 0.f ? a0 : 0.2f * a0;
        a1 = a1 > 0.f ? a1 : 0.2f * a1;
        float w0 = __expf(fminf(a0, 60.f));
        float w1 = __expf(fminf(a1, 60.f));
        bfrag8 v0 = *(const bfrag8*)(h + (size_t)i0 * 512 + lane * 8);
        bfrag8 v1 = *(const bfrag8*)(h + (size_t)i1 * 512 + lane * 8);
        den += w0 + w1;
#pragma unroll
        for (int j = 0; j < 8; ++j)
            acc[j] += w0 * bf2f((unsigned short)v0[j]) + w1 * bf2f((unsigned short)v1[j]);
    }
    for (; k < s1; ++k) {
        int i0 = csrc[k];
        float a = as_[(size_t)i0 * 8 + myh] + adn;
        a = a > 0.f ? a : 0.2f * a;
        float w = __expf(fminf(a, 60.f));
        bfrag8 v0 = *(const bfrag8*)(h + (size_t)i0 * 512 + lane * 8);
        den += w;
#pragma unroll
        for (int j = 0; j < 8; ++j) acc[j] += w * bf2f((unsigned short)v0[j]);
    }
    float rden = 1.f / (den + 1e-16f);
    bfrag8 o;
#pragma unroll
    for (int j = 0; j < 8; ++j) {
        float v = acc[j] * rden + bias[lane * 8 + j];
        o[j] = (short)f2bf(v > 0.f ? v : 0.f);
    }
    *(bfrag8*)(outp + (size_t)node * 512 + lane * 8) = o;
}

// ---------- single-head gather (64-wide) ----------
template<bool OBF>
__global__ __launch_bounds__(256) void gather1(const int* __restrict__ csrc,
                                               const int* __restrict__ rs,
                                               const float* __restrict__ as_,
                                               const float* __restrict__ ad_,
                                               const unsigned short* __restrict__ h,
                                               const float* __restrict__ bias,
                                               void* __restrict__ outp, int N) {
    int node = (int)((blockIdx.x * 256u + threadIdx.x) >> 6);
    int lane = threadIdx.x & 63;
    if (node >= N) return;
    int s0 = rs[node], s1 = rs[node + 1];
    float adn = ad_[node];
    float den = 0.f, acc = 0.f;
    int k = s0;
    for (; k + 4 <= s1; k += 4) {
        int i0 = csrc[k], i1 = csrc[k + 1], i2 = csrc[k + 2], i3 = csrc[k + 3];
        float a0 = as_[i0] + adn, a1 = as_[i1] + adn, a2 = as_[i2] + adn, a3 = as_[i3] + adn;
        a0 = a0 > 0.f ? a0 : 0.2f * a0;  a1 = a1 > 0.f ? a1 : 0.2f * a1;
        a2 = a2 > 0.f ? a2 : 0.2f * a2;  a3 = a3 > 0.f ? a3 : 0.2f * a3;
        float w0 = __expf(fminf(a0, 60.f)), w1 = __expf(fminf(a1, 60.f));
        float w2 = __expf(fminf(a2, 60.f)), w3 = __expf(fminf(a3, 60.f));
        float h0 = bf2f(h[(size_t)i0 * 64 + lane]);
        float h1 = bf2f(h[(size_t)i1 * 64 + lane]);
        float h2 = bf2f(h[(size_t)i2 * 64 + lane]);
        float h3 = bf2f(h[(size_t)i3 * 64 + lane]);
        den += (w0 + w1) + (w2 + w3);
        acc += w0 * h0;  acc += w1 * h1;  acc += w2 * h2;  acc += w3 * h3;
    }
    for (; k < s1; ++k) {
        int i0 = csrc[k];
        float a = as_[i0] + adn;
        a = a > 0.f ? a : 0.2f * a;
        float w = __expf(fminf(a, 60.f));
        den += w;
        acc += w * bf2f(h[(size_t)i0 * 64 + lane]);
    }
    float v = acc / (den + 1e-16f) + bias[lane];
    v = v > 0.f ? v : 0.f;
    if (OBF) ((unsigned short*)outp)[(size_t)node * 64 + lane] = f2bf(v);
    else     ((float*)outp)[(size_t)node * 64 + lane] = v;
}

// ---------- fused mean-pool + readout (sorted batch, one wave per graph) ----------
__global__ __launch_bounds__(256) void pool_readout(const float* __restrict__ h2,
                                                    const int* __restrict__ gstart,
                                                    const float* __restrict__ Wf,
                                                    const float* __restrict__ bf,
                                                    float* __restrict__ out, int G) {
    int g = (int)((blockIdx.x * 256u + threadIdx.x) >> 6);
    int lane = threadIdx.x & 63;
    if (g >= G) return;
    int s0 = gstart[g], s1 = gstart[g + 1];
    float acc = 0.f;
    int i = s0;
    for (; i + 2 <= s1; i += 2) {
        acc += h2[(size_t)i * 64 + lane];
        acc += h2[(size_t)(i + 1) * 64 + lane];
    }
    if (i < s1) acc += h2[(size_t)i * 64 + lane];
    float c = (float)(s1 - s0);
    c = c < 1.f ? 1.f : c;
    float v = acc / c * Wf[lane];
#pragma unroll
    for (int off = 32; off; off >>= 1) v += __shfl_xor(v, off);
    if (lane == 0) out[g] = v + bf[0];
}

extern "C" void kernel_launch(void* const* d_in, const int* in_sizes, int n_in,
                              void* d_out, int out_size, void* d_ws, size_t ws_size,
                              hipStream_t stream) {
    const float* x        = (const float*)d_in[0];
    const int*   ei       = (const int*)d_in[1];
    const int*   batch    = (const int*)d_in[2];
    const float* W1       = (const float*)d_in[3];
    const float* att_src1 = (const float*)d_in[4];
    const float* att_dst1 = (const float*)d_in[5];
    const float* b1       = (const float*)d_in[6];
    const float* W2       = (const float*)d_in[7];
    const float* att_src2 = (const float*)d_in[8];
    const float* att_dst2 = (const float*)d_in[9];
    const float* b2       = (const float*)d_in[10];
    const float* Wf       = (const float*)d_in[11];
    const float* bf       = (const float*)d_in[12];
    float* out = (float*)d_out;

    const int N = in_sizes[2];        // 100000
    const int E = in_sizes[1] / 2;    // 400000
    const int G = out_size;           // 4096

    const int nb = (N + SCAN_BLK - 1) / SCAN_BLK;
    const int nodeWaveGrid = (int)(((size_t)N * 64 + 255) / 256);
    const int edgeGrid = (E + N + 255) / 256;
    const int gemmGrid = (N + 127) / 128;

    // ---- common small buffers at the head of ws ----
    char* base = (char*)d_ws;
    size_t off = 0;
    auto alloc = [&](size_t bytes) { char* p = base + off; off += (bytes + 255) & ~255llu; return p; };
    unsigned short* wf1   = (unsigned short*)alloc(131072);
    unsigned short* wf2   = (unsigned short*)alloc(65536);
    float* as1            = (float*)alloc((size_t)N * 8 * 4);
    float* ad1            = (float*)alloc((size_t)N * 8 * 4);
    int*   cnt_i          = (int*)alloc((size_t)N * 4);
    int*   rs             = (int*)alloc((size_t)(N + 1) * 4);
    int*   csrc           = (int*)alloc((size_t)(E + N) * 4);
    int*   bsum           = (int*)alloc(1024);
    int*   gstart         = (int*)alloc((size_t)(G + 1) * 4);
    unsigned short* x_bf  = (unsigned short*)alloc((size_t)N * 128 * 2);
    float* ob2            = (float*)x_bf;   // alias: x_bf dead before ob2 written
    unsigned short* h2bf  = (unsigned short*)alloc((size_t)N * 64 * 2);
    size_t commonEnd = off;

    // fused-path big buffers
    size_t fusedNeed = commonEnd + 2 * (((size_t)N * 512 * 2 + 255) & ~255llu);
    bool fused = ws_size >= fusedNeed;

    // ---- shared prologue ----
    cvt_f32_bf16<<<2048, 256, 0, stream>>>(x, x_bf, (size_t)N * 128);
    prep_w1<<<(8 * 4 * 4 * 64 * 8) / 256, 256, 0, stream>>>(W1, wf1);
    prep_w2<<<(16 * 4 * 64 * 8) / 256, 256, 0, stream>>>(W2, wf2);

    zero_i32<<<512, 256, 0, stream>>>(cnt_i, N);
    hist_kernel<<<edgeGrid, 256, 0, stream>>>(ei, cnt_i, E, N);
    scan1<<<nb, 256, 0, stream>>>(cnt_i, rs, bsum, N);
    scan2<<<1, 1, 0, stream>>>(bsum, rs, nb, N);
    scan3<<<(N + 255) / 256, 256, 0, stream>>>(rs, bsum, N);
    zero_i32<<<512, 256, 0, stream>>>(cnt_i, N);
    scatter_kernel<<<edgeGrid, 256, 0, stream>>>(ei, rs, cnt_i, csrc, E, N);
    gstart_build<<<(N + 256) / 256, 256, 0, stream>>>(batch, gstart, N, G);

    if (fused) {
        unsigned short* h1_bf  = (unsigned short*)alloc((size_t)N * 512 * 2);
        unsigned short* ob1_bf = (unsigned short*)alloc((size_t)N * 512 * 2);

        // layer 1: one GEMM for all heads, one gather for all heads
        dim3 g1(gemmGrid, 8);
        gemm_l1<<<g1, 256, 0, stream>>>(x_bf, wf1, h1_bf, N, 512, 8,
                                        att_src1, att_dst1, as1, ad1);
        gather8<<<nodeWaveGrid, 256, 0, stream>>>(csrc, rs, as1, ad1, h1_bf, b1, ob1_bf, N);

        // layer 2 GEMM: K=512, fused attn2 dots (as1/ad1 reused with stride 1)
        gemm_l2_k512<<<gemmGrid, 256, 0, stream>>>(ob1_bf, wf2, h2bf, N,
                                                   att_src2, att_dst2, as1, ad1);
        gather1<false><<<nodeWaveGrid, 256, 0, stream>>>(csrc, rs, as1, ad1, h2bf, b2, ob2, N);
    } else {
        // fallback: per-head streaming (round-4 structure)
        unsigned short* hb_bf = (unsigned short*)alloc((size_t)N * 64 * 2);
        unsigned short* ob_bf = (unsigned short*)alloc((size_t)N * 64 * 2);
        float* h2acc          = (float*)alloc((size_t)N * 64 * 4);

        for (int h = 0; h < 8; ++h) {
            dim3 g1(gemmGrid, 1);
            gemm_l1<<<g1, 256, 0, stream>>>(x_bf, wf1 + (size_t)h * 8192, hb_bf, N, 64, 1,
                                            att_src1 + h * 64, att_dst1 + h * 64, as1, ad1);
            gather1<true><<<nodeWaveGrid, 256, 0, stream>>>(csrc, rs, as1, ad1, hb_bf, b1 + h * 64, ob_bf, N);
            if (h == 0) {
                gemm_acc<false, true, false, false><<<gemmGrid, 256, 0, stream>>>(
                    ob_bf, wf2, h2acc, nullptr, N, nullptr, nullptr, nullptr, nullptr);
            } else if (h < 7) {
                gemm_acc<true, true, false, false><<<gemmGrid, 256, 0, stream>>>(
                    ob_bf, wf2 + (size_t)h * 4096, h2acc, nullptr, N, nullptr, nullptr, nullptr, nullptr);
            } else {
                gemm_acc<true, false, true, true><<<gemmGrid, 256, 0, stream>>>(
                    ob_bf, wf2 + (size_t)h * 4096, h2acc, h2bf, N,
                    att_src2, att_dst2, as1, ad1);
            }
        }
        gather1<false><<<nodeWaveGrid, 256, 0, stream>>>(csrc, rs, as1, ad1, h2bf, b2, ob2, N);
    }

    // ---- fused pool + readout ----
    pool_readout<<<(G * 64 + 255) / 256, 256, 0, stream>>>(ob2, gstart, Wf, bf, out, G);
}